// Round 3
// baseline (524.908 us; speedup 1.0000x reference)
//
#include <hip/hip_runtime.h>
#include <cstdint>

#define NB 8
#define NA 100000
#define NC 80
#define TOPN 1000
#define MAXOBJ 100
#define CAND_CAP 2048
#define MIN_SCORE 0.05f
#define NMS_THR 0.5f

// ---------------- K1: per-anchor max/argmax + fused hist pass 1 ----------------
// Block = 320 threads handles 64 anchors (64*20 = 1280 float4). Four independent
// coalesced float4 loads per thread (4x MLP). LDS stride 21 -> conflict-free reduce.
__global__ __launch_bounds__(320) void k_scores(const float* __restrict__ cls,
                                                unsigned int* __restrict__ keys,
                                                int* __restrict__ clsid,
                                                unsigned int* __restrict__ hist1) {
    __shared__ float sval[64 * 21];
    __shared__ int sidx[64 * 21];
    const int b = blockIdx.y;
    const int a0 = blockIdx.x * 64;
    const int t = threadIdx.x;
    const float4* base = (const float4*)(cls + ((size_t)b * NA + a0) * NC);
    const int fmax = (NA - a0) * 20 - 1;  // last valid float4 index for this block

    int f0 = t, f1 = 320 + t, f2 = 640 + t, f3 = 960 + t;
    float4 v0 = base[min(f0, fmax)];
    float4 v1 = base[min(f1, fmax)];
    float4 v2 = base[min(f2, fmax)];
    float4 v3 = base[min(f3, fmax)];

#define REDUCE4(v, f)                                                   \
    {                                                                   \
        float m = v.x; int ix = 0;                                      \
        if (v.y > m) { m = v.y; ix = 1; }                               \
        if (v.z > m) { m = v.z; ix = 2; }                               \
        if (v.w > m) { m = v.w; ix = 3; }                               \
        int al = (f) / 20, e = (f) % 20;                                \
        sval[al * 21 + e] = m;                                          \
        sidx[al * 21 + e] = e * 4 + ix;                                 \
    }
    REDUCE4(v0, f0) REDUCE4(v1, f1) REDUCE4(v2, f2) REDUCE4(v3, f3)
#undef REDUCE4
    __syncthreads();

    if (t < 64) {
        const int a = a0 + t;
        unsigned int key = 0u;
        if (a < NA) {
            float vm = sval[t * 21]; int vi = sidx[t * 21];
            for (int j = 1; j < 20; ++j) {
                float x = sval[t * 21 + j];
                if (x > vm) { vm = x; vi = sidx[t * 21 + j]; }
            }
            key = (vm > MIN_SCORE) ? __float_as_uint(vm) : 0u;
            size_t o = (size_t)b * NA + a;
            keys[o] = key;
            clsid[o] = vi;
        }
        // wave-aggregated fire-and-forget hist1 atomics (~1-2 distinct bins/wave)
        const int lane = t;
        int bin = (int)(key >> 21);
        bool pred = (a < NA) && (key != 0u);
        unsigned long long active = __ballot(pred);
        while (active) {
            int leader = (int)__builtin_ctzll(active);
            int lbin = __shfl(bin, leader);
            unsigned long long mask = __ballot(pred && (bin == lbin));
            if (lane == leader) atomicAdd(&hist1[b * 2048 + lbin], (unsigned int)__popcll(mask));
            active &= ~mask;
        }
    }
}

// ---------------- parallel wave suffix-scan threshold search ----------------
// One wave per image; finds bin with (count strictly above) < rank <= (count incl).
__device__ inline void top_threshold_g(const unsigned int* __restrict__ h, int nbins,
                                       int minbin, unsigned int rank,
                                       int* __restrict__ out_bin,
                                       unsigned int* __restrict__ out_above) {
    const int lane = threadIdx.x;
    const int chunk = nbins >> 6;
    const int hi = nbins - 1 - lane * chunk;
    const int lo = hi - chunk + 1;
    unsigned int s = 0;
    for (int i = hi; i >= lo; --i)
        if (i >= minbin) s += h[i];
    unsigned int incl = s;
    for (int d = 1; d < 64; d <<= 1) {
        unsigned int o = __shfl_up(incl, d);
        if (lane >= d) incl += o;
    }
    unsigned int pre = incl - s;
    bool hit = (pre < rank) && (incl >= rank);
    unsigned long long m = __ballot(hit);
    if (m == 0ull) {
        if (lane == 0) { *out_bin = -1; *out_above = 0; }
        return;
    }
    if (hit) {
        unsigned int cum = pre;
        int fb = -1;
        for (int i = hi; i >= lo; --i) {
            if (i < minbin) break;
            unsigned int c = h[i];
            if (cum + c >= rank) { fb = i; break; }
            cum += c;
        }
        *out_bin = fb;
        *out_above = cum;
    }
}

__global__ __launch_bounds__(64) void k_scan(int mode, const unsigned int* __restrict__ h1,
                                             const unsigned int* __restrict__ h2,
                                             const unsigned int* __restrict__ h3,
                                             int* prefix1, unsigned int* above1,
                                             int* prefix2, unsigned int* above2,
                                             unsigned int* T) {
    const int b = blockIdx.x;
    __shared__ int s_bin;
    __shared__ unsigned int s_above;
    if (mode == 1) {
        top_threshold_g(h1 + b * 2048, 2048, 1, TOPN, &s_bin, &s_above);
        __syncthreads();
        if (threadIdx.x == 0) {
            prefix1[b] = s_bin;
            above1[b] = s_above;
            if (s_bin < 0) T[b] = 1u;  // fewer than TOPN valid
        }
    } else if (mode == 2) {
        if (prefix1[b] < 0) return;
        top_threshold_g(h2 + b * 2048, 2048, 0, TOPN - above1[b], &s_bin, &s_above);
        __syncthreads();
        if (threadIdx.x == 0) {
            if (s_bin < 0) { prefix2[b] = -1; T[b] = 1u; }
            else { prefix2[b] = (prefix1[b] << 11) | s_bin; above2[b] = above1[b] + s_above; }
        }
    } else {
        if (prefix1[b] < 0 || prefix2[b] < 0) return;
        top_threshold_g(h3 + b * 1024, 1024, 0, TOPN - above2[b], &s_bin, &s_above);
        __syncthreads();
        if (threadIdx.x == 0)
            T[b] = (s_bin < 0) ? 1u : (((unsigned int)prefix2[b] << 10) | (unsigned int)s_bin);
    }
}

// ---------------- grid-parallel hist passes 2/3 (2048 keys per 256-thread block) ----------------
__global__ __launch_bounds__(256) void k_hist2(const unsigned int* __restrict__ keys,
                                               const int* __restrict__ prefix1,
                                               unsigned int* __restrict__ hist2) {
    __shared__ unsigned int lh[2048];
    const int b = blockIdx.y;
    const int p = prefix1[b];
    if (p < 0) return;
    const int t = threadIdx.x;
    const int a0 = blockIdx.x * 2048;
    const unsigned int* kb = keys + (size_t)b * NA;
    for (int i = t; i < 2048; i += 256) lh[i] = 0;
    __syncthreads();
    for (int c = 0; c < 8; ++c) {
        int a = a0 + c * 256 + t;
        if (a < NA) {
            unsigned int key = kb[a];
            if ((int)(key >> 21) == p) atomicAdd(&lh[(key >> 10) & 0x7FFu], 1u);
        }
    }
    __syncthreads();
    for (int i = t; i < 2048; i += 256)
        if (lh[i]) atomicAdd(&hist2[b * 2048 + i], lh[i]);
}

__global__ __launch_bounds__(256) void k_hist3(const unsigned int* __restrict__ keys,
                                               const int* __restrict__ prefix1,
                                               const int* __restrict__ prefix2,
                                               unsigned int* __restrict__ hist3) {
    __shared__ unsigned int lh[1024];
    const int b = blockIdx.y;
    if (prefix1[b] < 0 || prefix2[b] < 0) return;
    const unsigned int pref = (unsigned int)prefix2[b];
    const int t = threadIdx.x;
    const int a0 = blockIdx.x * 2048;
    const unsigned int* kb = keys + (size_t)b * NA;
    for (int i = t; i < 1024; i += 256) lh[i] = 0;
    __syncthreads();
    for (int c = 0; c < 8; ++c) {
        int a = a0 + c * 256 + t;
        if (a < NA) {
            unsigned int key = kb[a];
            if ((key >> 10) == pref) atomicAdd(&lh[key & 0x3FFu], 1u);
        }
    }
    __syncthreads();
    for (int i = t; i < 1024; i += 256)
        if (lh[i]) atomicAdd(&hist3[b * 1024 + i], lh[i]);
}

// ---------------- collect keys >= T, ballot-compacted ----------------
__global__ __launch_bounds__(256) void k_collect(const unsigned int* __restrict__ keys,
                                                 const unsigned int* __restrict__ T,
                                                 unsigned int* __restrict__ n_cand,
                                                 unsigned long long* __restrict__ cand) {
    const int b = blockIdx.y;
    const int t = threadIdx.x;
    const int lane = t & 63;
    const int a0 = blockIdx.x * 2048;
    const unsigned int* kb = keys + (size_t)b * NA;
    const unsigned int thr = T[b];
    for (int c = 0; c < 8; ++c) {
        int a = a0 + c * 256 + t;
        unsigned int key = (a < NA) ? kb[a] : 0u;
        bool w = (key >= thr) && (key != 0u);
        unsigned long long m = __ballot(w);
        if (m) {
            int leader = (int)__builtin_ctzll(m);
            unsigned int base_slot = 0;
            if (lane == leader) base_slot = atomicAdd(&n_cand[b], (unsigned int)__popcll(m));
            base_slot = __shfl(base_slot, leader);
            unsigned int off = (unsigned int)__popcll(m & ((1ull << lane) - 1ull));
            unsigned int pos = base_slot + off;
            if (w && pos < CAND_CAP)
                cand[(size_t)b * CAND_CAP + pos] =
                    ((unsigned long long)key << 32) |
                    (unsigned long long)(0xFFFFFFFFu - (unsigned int)a);
        }
    }
}

// ---------------- final: sort + decode + NMS + output ----------------
__global__ __launch_bounds__(1024) void k_final(
    const unsigned long long* __restrict__ cand, const unsigned int* __restrict__ n_cand,
    const int* __restrict__ clsid, const float* __restrict__ reg, const float* __restrict__ anch,
    float* __restrict__ out) {
    __shared__ unsigned long long sk[CAND_CAP];
    __shared__ float4 sbox[TOPN];
    __shared__ float ss[TOPN];
    __shared__ float scl[TOPN];
    const int b = blockIdx.x;
    const int tid = threadIdx.x;
    float* out_s = out + b * MAXOBJ;
    float* out_c = out + NB * MAXOBJ + b * MAXOBJ;
    float* out_b = out + 2 * NB * MAXOBJ + b * MAXOBJ * 4;

    if (tid < MAXOBJ) { out_s[tid] = -1.0f; out_c[tid] = -1.0f; }
    if (tid < MAXOBJ * 4) out_b[tid] = 0.0f;

    int n = (int)n_cand[b]; if (n > CAND_CAP) n = CAND_CAP;
    for (int i = tid; i < CAND_CAP; i += 1024)
        sk[i] = (i < n) ? cand[(size_t)b * CAND_CAP + i] : 0ull;

    for (int k = 2; k <= CAND_CAP; k <<= 1)
        for (int j = k >> 1; j > 0; j >>= 1) {
            __syncthreads();
            for (int i = tid; i < CAND_CAP; i += 1024) {
                int ixj = i ^ j;
                if (ixj > i) {
                    unsigned long long x = sk[i], y = sk[ixj];
                    bool desc = ((i & k) == 0);
                    if (desc ? (x < y) : (x > y)) { sk[i] = y; sk[ixj] = x; }
                }
            }
        }
    __syncthreads();

    if (tid < TOPN) {
        unsigned long long e = sk[tid];
        unsigned int key = (unsigned int)(e >> 32);
        if (key != 0u) {
            int a = (int)(0xFFFFFFFFu - (unsigned int)e);
            size_t base = (size_t)b * NA + a;
            float4 r  = ((const float4*)reg)[base];
            float4 an = ((const float4*)anch)[base];
            float aw = an.z - an.x, ah = an.w - an.y;
            float acx = an.x + 0.5f * aw, acy = an.y + 0.5f * ah;
            float pw = expf(r.z) * aw, ph = expf(r.w) * ah;
            float pcx = r.x * aw + acx, pcy = r.y * ah + acy;
            float4 bx;
            bx.x = truncf(pcx - 0.5f * pw); bx.y = truncf(pcy - 0.5f * ph);
            bx.z = truncf(pcx + 0.5f * pw); bx.w = truncf(pcy + 0.5f * ph);
            sbox[tid] = bx;
            ss[tid] = __uint_as_float(key);
            scl[tid] = (float)clsid[base];
        } else {
            sbox[tid] = make_float4(0.f, 0.f, 0.f, 0.f);
            ss[tid] = -1.0f;
            scl[tid] = -1.0f;
        }
    }
    __syncthreads();
    if (tid >= 64) return;

    // wave 0: greedy NMS; kept boxes in registers distributed across lanes
    const int lane = tid;
    float k0x1 = 0, k0y1 = 0, k0x2 = 0, k0y2 = 0, k0a = 0;
    float k1x1 = 0, k1y1 = 0, k1x2 = 0, k1y2 = 0, k1a = 0;
    int kc = 0;
    for (int i = 0; i < TOPN; ++i) {
        float4 bi = sbox[i];
        float si = ss[i];
        if (!(si > MIN_SCORE)) break;
        float areai = fmaxf((bi.z - bi.x) * (bi.w - bi.y), 1e-4f);
        bool sup = false;
        if (lane < kc) {
            float ix = fminf(k0x2, bi.z) - fmaxf(k0x1, bi.x);
            float iy = fminf(k0y2, bi.w) - fmaxf(k0y1, bi.y);
            float inter = fmaxf(ix, 0.0f) * fmaxf(iy, 0.0f);
            float uni = fmaxf(k0a + areai - inter, 1e-4f);
            sup = (inter / uni) >= NMS_THR;
        }
        if (lane + 64 < kc) {
            float ix = fminf(k1x2, bi.z) - fmaxf(k1x1, bi.x);
            float iy = fminf(k1y2, bi.w) - fmaxf(k1y1, bi.y);
            float inter = fmaxf(ix, 0.0f) * fmaxf(iy, 0.0f);
            float uni = fmaxf(k1a + areai - inter, 1e-4f);
            sup = sup || ((inter / uni) >= NMS_THR);
        }
        if (__ballot(sup) == 0ull) {
            if (lane == 0) {
                out_s[kc] = si;
                out_c[kc] = scl[i];
                out_b[kc * 4 + 0] = bi.x; out_b[kc * 4 + 1] = bi.y;
                out_b[kc * 4 + 2] = bi.z; out_b[kc * 4 + 3] = bi.w;
            }
            if (kc < 64) {
                if (lane == kc) { k0x1 = bi.x; k0y1 = bi.y; k0x2 = bi.z; k0y2 = bi.w; k0a = areai; }
            } else {
                if (lane == kc - 64) { k1x1 = bi.x; k1y1 = bi.y; k1x2 = bi.z; k1y2 = bi.w; k1a = areai; }
            }
            ++kc;
            if (kc >= MAXOBJ) break;
        }
    }
}

extern "C" void kernel_launch(void* const* d_in, const int* in_sizes, int n_in,
                              void* d_out, int out_size, void* d_ws, size_t ws_size,
                              hipStream_t stream) {
    const float* cls  = (const float*)d_in[0];
    const float* reg  = (const float*)d_in[1];
    const float* anch = (const float*)d_in[2];
    float* out = (float*)d_out;
    char* ws = (char*)d_ws;

    unsigned int* keys = (unsigned int*)ws;                          // 3,200,000 B
    int* clsid = (int*)(ws + 3200000);                               // 3,200,000 B
    unsigned long long* cand = (unsigned long long*)(ws + 6400000);  // 131,072 B
    char* zbase = ws + 6400000 + 131072;
    unsigned int* h1 = (unsigned int*)zbase;                         // 65,536 B
    unsigned int* h2 = (unsigned int*)(zbase + 65536);               // 65,536 B
    unsigned int* h3 = (unsigned int*)(zbase + 131072);              // 32,768 B
    unsigned int* n_cand  = (unsigned int*)(zbase + 163840);         // 32 B
    int* prefix1          = (int*)(zbase + 163840 + 32);
    unsigned int* above1  = (unsigned int*)(zbase + 163840 + 64);
    int* prefix2          = (int*)(zbase + 163840 + 96);
    unsigned int* above2  = (unsigned int*)(zbase + 163840 + 128);
    unsigned int* T       = (unsigned int*)(zbase + 163840 + 160);

    hipMemsetAsync(zbase, 0, 163840 + 192, stream);

    dim3 gscore((NA + 63) / 64, NB);   // 1563 x 8, 64 anchors / 320-thread block
    dim3 ghist((NA + 2047) / 2048, NB); // 49 x 8, 2048 keys / 256-thread block
    k_scores<<<gscore, 320, 0, stream>>>(cls, keys, clsid, h1);
    k_scan<<<NB, 64, 0, stream>>>(1, h1, h2, h3, prefix1, above1, prefix2, above2, T);
    k_hist2<<<ghist, 256, 0, stream>>>(keys, prefix1, h2);
    k_scan<<<NB, 64, 0, stream>>>(2, h1, h2, h3, prefix1, above1, prefix2, above2, T);
    k_hist3<<<ghist, 256, 0, stream>>>(keys, prefix1, prefix2, h3);
    k_scan<<<NB, 64, 0, stream>>>(3, h1, h2, h3, prefix1, above1, prefix2, above2, T);
    k_collect<<<ghist, 256, 0, stream>>>(keys, T, n_cand, cand);
    k_final<<<NB, 1024, 0, stream>>>(cand, n_cand, clsid, reg, anch, out);
}

// Round 4
// 498.338 us; speedup vs baseline: 1.0533x; 1.0533x over previous
//
#include <hip/hip_runtime.h>
#include <cstdint>

#define NB 8
#define NA 100000
#define NC 80
#define TOPN 1000
#define MAXOBJ 100
#define CAND1 16384   // prefilter candidate cap per image
#define SORTN 2048    // final sort size
#define MIN_SCORE 0.05f
#define NMS_THR 0.5f

// ---------------- K1: per-anchor max/argmax + prefilter append ----------------
// Block = 320 threads handles 64 anchors (1280 float4). 4 coalesced float4/thread.
// LDS stride 21 -> conflict-free reduce. Wave 0 appends candidates >= 0.999.
__global__ __launch_bounds__(320) void k_scores(const float* __restrict__ cls,
                                                unsigned int* __restrict__ keys,
                                                int* __restrict__ clsid,
                                                unsigned long long* __restrict__ cand,
                                                unsigned int* __restrict__ n_cand) {
    __shared__ float sval[64 * 21];
    __shared__ int sidx[64 * 21];
    const int b = blockIdx.y;
    const int a0 = blockIdx.x * 64;
    const int t = threadIdx.x;
    const float4* base = (const float4*)(cls + ((size_t)b * NA + a0) * NC);
    const int fmax = (NA - a0) * 20 - 1;

    int f0 = t, f1 = 320 + t, f2 = 640 + t, f3 = 960 + t;
    float4 v0 = base[min(f0, fmax)];
    float4 v1 = base[min(f1, fmax)];
    float4 v2 = base[min(f2, fmax)];
    float4 v3 = base[min(f3, fmax)];

#define REDUCE4(v, f)                                                   \
    {                                                                   \
        float m = v.x; int ix = 0;                                      \
        if (v.y > m) { m = v.y; ix = 1; }                               \
        if (v.z > m) { m = v.z; ix = 2; }                               \
        if (v.w > m) { m = v.w; ix = 3; }                               \
        int al = (f) / 20, e = (f) % 20;                                \
        sval[al * 21 + e] = m;                                          \
        sidx[al * 21 + e] = e * 4 + ix;                                 \
    }
    REDUCE4(v0, f0) REDUCE4(v1, f1) REDUCE4(v2, f2) REDUCE4(v3, f3)
#undef REDUCE4
    __syncthreads();

    if (t < 64) {
        const int a = a0 + t;
        unsigned int key = 0u;
        if (a < NA) {
            float vm = sval[t * 21]; int vi = sidx[t * 21];
            for (int j = 1; j < 20; ++j) {
                float x = sval[t * 21 + j];
                if (x > vm) { vm = x; vi = sidx[t * 21 + j]; }
            }
            key = (vm > MIN_SCORE) ? __float_as_uint(vm) : 0u;
            size_t o = (size_t)b * NA + a;
            keys[o] = key;
            clsid[o] = vi;
        }
        // prefilter: append anchors with score >= 0.999 (expected ~7.7k/image)
        const unsigned int T0 = __float_as_uint(0.999f);
        bool w = (a < NA) && (key >= T0);
        unsigned long long m = __ballot(w);
        if (m) {
            int leader = (int)__builtin_ctzll(m);
            unsigned int bs = 0;
            if (t == leader) bs = atomicAdd(&n_cand[b], (unsigned int)__popcll(m));
            bs = __shfl(bs, leader);
            unsigned int pos = bs + (unsigned int)__popcll(m & ((1ull << t) - 1ull));
            if (w && pos < CAND1)
                cand[(size_t)b * CAND1 + pos] =
                    ((unsigned long long)key << 32) |
                    (unsigned long long)(0xFFFFFFFFu - (unsigned int)a);
        }
    }
}

// wave-aggregated LDS histogram add (for concentrated bins)
__device__ inline void wave_agg_hist(unsigned int* lh, int bin, bool pred) {
    unsigned long long active = __ballot(pred);
    const int lane = threadIdx.x & 63;
    while (active) {
        int leader = (int)__builtin_ctzll(active);
        int lbin = __shfl(bin, leader);
        unsigned long long mask = __ballot(pred && (bin == lbin));
        if (lane == leader) atomicAdd(&lh[lbin], (unsigned int)__popcll(mask));
        active &= ~mask;
    }
}

// one wave: suffix-scan threshold search over LDS histogram
__device__ inline void top_threshold(const unsigned int* lh, int nbins, int minbin,
                                     unsigned int rank, int* out_bin, unsigned int* out_above) {
    const int lane = threadIdx.x;  // caller guarantees tid < 64
    const int chunk = nbins >> 6;
    const int hi = nbins - 1 - lane * chunk;
    const int lo = hi - chunk + 1;
    unsigned int s = 0;
    for (int i = hi; i >= lo; --i)
        if (i >= minbin) s += lh[i];
    unsigned int incl = s;
    for (int d = 1; d < 64; d <<= 1) {
        unsigned int o = __shfl_up(incl, d);
        if (lane >= d) incl += o;
    }
    unsigned int pre = incl - s;
    bool hit = (pre < rank) && (incl >= rank);
    unsigned long long m = __ballot(hit);
    if (m == 0ull) {
        if (lane == 0) { *out_bin = -1; *out_above = 0; }
        return;
    }
    if (hit) {
        unsigned int cum = pre;
        int fb = -1;
        for (int i = hi; i >= lo; --i) {
            if (i < minbin) break;
            unsigned int c = lh[i];
            if (cum + c >= rank) { fb = i; break; }
            cum += c;
        }
        *out_bin = fb;
        *out_above = cum;
    }
}

// ---------------- K2: exact top-1000 select + sort + decode + NMS + output ----------------
// Fast path: radix over the ~7.7k-candidate list (L2-hot). Slow path (candidate
// underflow/overflow, never on this bench): identical radix over full keys[].
__global__ __launch_bounds__(1024) void k_select(
    const unsigned int* __restrict__ keys, const int* __restrict__ clsid,
    const unsigned long long* __restrict__ cand, const unsigned int* __restrict__ n_cand,
    const float* __restrict__ reg, const float* __restrict__ anch,
    float* __restrict__ out) {
    __shared__ unsigned int lh[2048];
    __shared__ unsigned long long sk[SORTN];
    __shared__ float4 sbox[TOPN];
    __shared__ float ss[TOPN];
    __shared__ float scl[TOPN];
    __shared__ int s_bin;
    __shared__ unsigned int s_above;
    __shared__ unsigned int s_cnt;

    const int b = blockIdx.x;
    const int tid = threadIdx.x;
    const int lane = tid & 63;
    const unsigned int* kb = keys + (size_t)b * NA;
    const unsigned long long* cb = cand + (size_t)b * CAND1;
    float* out_s = out + b * MAXOBJ;
    float* out_c = out + NB * MAXOBJ + b * MAXOBJ;
    float* out_b = out + 2 * NB * MAXOBJ + b * MAXOBJ * 4;

    if (tid < MAXOBJ) { out_s[tid] = -1.0f; out_c[tid] = -1.0f; }
    if (tid < MAXOBJ * 4) out_b[tid] = 0.0f;

    const unsigned int n0 = n_cand[b];
    const bool fast = (n0 >= TOPN) && (n0 <= CAND1);
    const int N = fast ? (int)n0 : NA;

    // ---- radix pass 1: bins = key >> 21 (concentrated -> wave-aggregated) ----
    for (int i = tid; i < 2048; i += 1024) lh[i] = 0;
    __syncthreads();
    for (int base = 0; base < N; base += 1024) {
        int i = base + tid;
        unsigned int k = 0u;
        if (i < N) k = fast ? (unsigned int)(cb[i] >> 32) : kb[i];
        wave_agg_hist(lh, (int)(k >> 21), (i < N) && (k != 0u));
    }
    __syncthreads();
    if (tid < 64) top_threshold(lh, 2048, 1, TOPN, &s_bin, &s_above);
    __syncthreads();
    const int p1 = s_bin;
    const unsigned int above1 = s_above;

    unsigned int T;
    if (p1 < 0) {
        T = 1u;  // fewer than TOPN valid: take all nonzero
    } else {
        // ---- pass 2: bits[20:10] within bin p1 (spread -> plain atomics) ----
        __syncthreads();
        for (int i = tid; i < 2048; i += 1024) lh[i] = 0;
        __syncthreads();
        for (int base = 0; base < N; base += 1024) {
            int i = base + tid;
            if (i < N) {
                unsigned int k = fast ? (unsigned int)(cb[i] >> 32) : kb[i];
                if ((int)(k >> 21) == p1) atomicAdd(&lh[(k >> 10) & 0x7FFu], 1u);
            }
        }
        __syncthreads();
        if (tid < 64) top_threshold(lh, 2048, 0, TOPN - above1, &s_bin, &s_above);
        __syncthreads();
        const int p2 = s_bin;
        const unsigned int above2 = above1 + s_above;
        if (p2 < 0) {
            T = 1u;
        } else {
            // ---- pass 3: low 10 bits within (p1,p2) ----
            const unsigned int pref = ((unsigned int)p1 << 11) | (unsigned int)p2;
            __syncthreads();
            for (int i = tid; i < 1024; i += 1024) lh[i] = 0;
            __syncthreads();
            for (int base = 0; base < N; base += 1024) {
                int i = base + tid;
                if (i < N) {
                    unsigned int k = fast ? (unsigned int)(cb[i] >> 32) : kb[i];
                    if ((k >> 10) == pref) atomicAdd(&lh[k & 0x3FFu], 1u);
                }
            }
            __syncthreads();
            if (tid < 64) top_threshold(lh, 1024, 0, TOPN - above2, &s_bin, &s_above);
            __syncthreads();
            T = (s_bin < 0) ? 1u : ((pref << 10) | (unsigned int)s_bin);
        }
    }
    __syncthreads();

    // ---- collect entries >= T (ballot-compacted) ----
    for (int i = tid; i < SORTN; i += 1024) sk[i] = 0ull;
    if (tid == 0) s_cnt = 0;
    __syncthreads();
    for (int base = 0; base < N; base += 1024) {
        int i = base + tid;
        unsigned long long e = 0ull;
        unsigned int k = 0u;
        if (i < N) {
            if (fast) { e = cb[i]; k = (unsigned int)(e >> 32); }
            else {
                k = kb[i];
                e = ((unsigned long long)k << 32) |
                    (unsigned long long)(0xFFFFFFFFu - (unsigned int)i);
            }
        }
        bool w = (k >= T) && (k != 0u);
        unsigned long long m = __ballot(w);
        if (m) {
            int leader = (int)__builtin_ctzll(m);
            unsigned int bs = 0;
            if (lane == leader) bs = atomicAdd(&s_cnt, (unsigned int)__popcll(m));
            bs = __shfl(bs, leader);
            unsigned int pos = bs + (unsigned int)__popcll(m & ((1ull << lane) - 1ull));
            if (w && pos < SORTN) sk[pos] = e;
        }
    }
    __syncthreads();

    // ---- bitonic sort SORTN, descending ----
    for (int k = 2; k <= SORTN; k <<= 1)
        for (int j = k >> 1; j > 0; j >>= 1) {
            __syncthreads();
            for (int i = tid; i < SORTN; i += 1024) {
                int ixj = i ^ j;
                if (ixj > i) {
                    unsigned long long x = sk[i], y = sk[ixj];
                    bool desc = ((i & k) == 0);
                    if (desc ? (x < y) : (x > y)) { sk[i] = y; sk[ixj] = x; }
                }
            }
        }
    __syncthreads();

    // ---- decode top TOPN ----
    if (tid < TOPN) {
        unsigned long long e = sk[tid];
        unsigned int key = (unsigned int)(e >> 32);
        if (key != 0u) {
            int a = (int)(0xFFFFFFFFu - (unsigned int)e);
            size_t base = (size_t)b * NA + a;
            float4 r  = ((const float4*)reg)[base];
            float4 an = ((const float4*)anch)[base];
            float aw = an.z - an.x, ah = an.w - an.y;
            float acx = an.x + 0.5f * aw, acy = an.y + 0.5f * ah;
            float pw = expf(r.z) * aw, ph = expf(r.w) * ah;
            float pcx = r.x * aw + acx, pcy = r.y * ah + acy;
            float4 bx;
            bx.x = truncf(pcx - 0.5f * pw); bx.y = truncf(pcy - 0.5f * ph);
            bx.z = truncf(pcx + 0.5f * pw); bx.w = truncf(pcy + 0.5f * ph);
            sbox[tid] = bx;
            ss[tid] = __uint_as_float(key);
            scl[tid] = (float)clsid[base];
        } else {
            sbox[tid] = make_float4(0.f, 0.f, 0.f, 0.f);
            ss[tid] = -1.0f;
            scl[tid] = -1.0f;
        }
    }
    __syncthreads();
    if (tid >= 64) return;

    // ---- wave 0: greedy NMS; kept boxes in registers across lanes ----
    float k0x1 = 0, k0y1 = 0, k0x2 = 0, k0y2 = 0, k0a = 0;
    float k1x1 = 0, k1y1 = 0, k1x2 = 0, k1y2 = 0, k1a = 0;
    int kc = 0;
    for (int i = 0; i < TOPN; ++i) {
        float4 bi = sbox[i];
        float si = ss[i];
        if (!(si > MIN_SCORE)) break;
        float areai = fmaxf((bi.z - bi.x) * (bi.w - bi.y), 1e-4f);
        bool sup = false;
        if (lane < kc) {
            float ix = fminf(k0x2, bi.z) - fmaxf(k0x1, bi.x);
            float iy = fminf(k0y2, bi.w) - fmaxf(k0y1, bi.y);
            float inter = fmaxf(ix, 0.0f) * fmaxf(iy, 0.0f);
            float uni = fmaxf(k0a + areai - inter, 1e-4f);
            sup = (inter / uni) >= NMS_THR;
        }
        if (lane + 64 < kc) {
            float ix = fminf(k1x2, bi.z) - fmaxf(k1x1, bi.x);
            float iy = fminf(k1y2, bi.w) - fmaxf(k1y1, bi.y);
            float inter = fmaxf(ix, 0.0f) * fmaxf(iy, 0.0f);
            float uni = fmaxf(k1a + areai - inter, 1e-4f);
            sup = sup || ((inter / uni) >= NMS_THR);
        }
        if (__ballot(sup) == 0ull) {
            if (lane == 0) {
                out_s[kc] = si;
                out_c[kc] = scl[i];
                out_b[kc * 4 + 0] = bi.x; out_b[kc * 4 + 1] = bi.y;
                out_b[kc * 4 + 2] = bi.z; out_b[kc * 4 + 3] = bi.w;
            }
            if (kc < 64) {
                if (lane == kc) { k0x1 = bi.x; k0y1 = bi.y; k0x2 = bi.z; k0y2 = bi.w; k0a = areai; }
            } else {
                if (lane == kc - 64) { k1x1 = bi.x; k1y1 = bi.y; k1x2 = bi.z; k1y2 = bi.w; k1a = areai; }
            }
            ++kc;
            if (kc >= MAXOBJ) break;
        }
    }
}

extern "C" void kernel_launch(void* const* d_in, const int* in_sizes, int n_in,
                              void* d_out, int out_size, void* d_ws, size_t ws_size,
                              hipStream_t stream) {
    const float* cls  = (const float*)d_in[0];
    const float* reg  = (const float*)d_in[1];
    const float* anch = (const float*)d_in[2];
    float* out = (float*)d_out;
    char* ws = (char*)d_ws;

    unsigned int* keys = (unsigned int*)ws;                          // 3,200,000 B
    int* clsid = (int*)(ws + 3200000);                               // 3,200,000 B
    unsigned long long* cand = (unsigned long long*)(ws + 6400000);  // 8*16384*8 = 1,048,576 B
    unsigned int* n_cand = (unsigned int*)(ws + 7448576);            // 32 B

    hipMemsetAsync(n_cand, 0, 32, stream);

    dim3 gscore((NA + 63) / 64, NB);  // 1563 x 8
    k_scores<<<gscore, 320, 0, stream>>>(cls, keys, clsid, cand, n_cand);
    k_select<<<NB, 1024, 0, stream>>>(keys, clsid, cand, n_cand, reg, anch, out);
}